// Round 6
// baseline (214.056 us; speedup 1.0000x reference)
//
#include <hip/hip_runtime.h>

// Problem constants (fixed by setup_inputs): B=32, C=256, H=W=64
#define BATCH 32
#define CHAN  256
#define HGT   64
#define WID   64
#define HW    4096   // HGT*WID

// Kernel 1: per-batch scatter-accumulated bilinear weight map A[b, 0:4096].
// One block per batch; LDS float atomicAdd. Mean (1/4096) folded in.
__global__ __launch_bounds__(256) void weight_map_kernel(
        const float* __restrict__ offset,   // [B, 2, H, W] fp32
        const float* __restrict__ ts_ptr,   // scalar fp32
        float* __restrict__ A)              // [B, 4096] fp32 (d_ws)
{
    const int b   = blockIdx.x;
    const int tid = threadIdx.x;

    __shared__ float acc[HW];   // 16 KiB
    for (int k = tid; k < HW; k += 256) acc[k] = 0.0f;
    __syncthreads();

    float ts = ts_ptr[0];
    ts = fminf(fmaxf(ts, 0.001f), 0.01f);

    const float* off_y = offset + (size_t)b * 2 * HW;   // offset[b,0]
    const float* off_x = off_y + HW;                    // offset[b,1]

    for (int p = tid; p < HW; p += 256) {
        const int i = p >> 6;
        const int j = p & 63;
        const float dy = off_y[p];
        const float dx = off_x[p];
        float y = fminf(fmaxf((float)i + ts * dy * 64.0f, 0.0f), 63.0f);
        float x = fminf(fmaxf((float)j + ts * dx * 64.0f, 0.0f), 63.0f);
        int y0 = (int)floorf(y); y0 = min(max(y0, 0), HGT - 2);
        int x0 = (int)floorf(x); x0 = min(max(x0, 0), WID - 2);
        const float wy = y - (float)y0;
        const float wx = x - (float)x0;
        const int base = (y0 << 6) + x0;
        atomicAdd(&acc[base],           (1.0f - wy) * (1.0f - wx));
        atomicAdd(&acc[base + 1],       (1.0f - wy) * wx);
        atomicAdd(&acc[base + WID],     wy * (1.0f - wx));
        atomicAdd(&acc[base + WID + 1], wy * wx);
    }
    __syncthreads();

    float* Ab = A + (size_t)b * HW;
    const float s = 1.0f / (float)HW;
    for (int k = tid; k < HW; k += 256) Ab[k] = acc[k] * s;
}

// Kernel 2: 4 planes per block (one per wave). A[b] is staged into LDS ONCE
// per block (cuts global A traffic 128 MiB -> 32 MiB), then each wave streams
// its 16 KiB plane from global (read exactly once) against LDS-resident A.
// 2048 blocks x 4 waves = 8192 waves — the config that sustained ~4 TB/s.
__global__ __launch_bounds__(256) void dot_kernel(
        const float* __restrict__ data,   // [B, C, H, W] fp32
        const float* __restrict__ A,      // [B, 4096] fp32
        float* __restrict__ out)          // [B, C] fp32
{
    __shared__ float As[HW];              // 16 KiB
    const int tid        = threadIdx.x;
    const int base_plane = blockIdx.x << 2;   // 4 consecutive planes
    const int b          = base_plane >> 8;   // 4 | 256 -> no batch straddle

    // Cooperative stage of A[b]: 256 threads x 4 float4 = 4096 floats.
    const float* Ab = A + (size_t)b * HW;
    #pragma unroll
    for (int k = 0; k < 4; ++k) {
        const int idx = k * 1024 + tid * 4;
        *reinterpret_cast<float4*>(&As[idx]) =
            *reinterpret_cast<const float4*>(Ab + idx);
    }
    __syncthreads();

    const int wv   = tid >> 6;
    const int lane = tid & 63;
    const float* plane = data + (size_t)(base_plane + wv) * HW;
    const int o = lane << 2;              // lane*4 floats

    float s0 = 0.0f, s1 = 0.0f, s2 = 0.0f, s3 = 0.0f;

    #pragma unroll
    for (int it = 0; it < 4; ++it) {
        const int idx = it * 1024 + o;    // 4 chunks of 256 floats per iter
        const float4 d0 = *reinterpret_cast<const float4*>(plane + idx);
        const float4 d1 = *reinterpret_cast<const float4*>(plane + idx + 256);
        const float4 d2 = *reinterpret_cast<const float4*>(plane + idx + 512);
        const float4 d3 = *reinterpret_cast<const float4*>(plane + idx + 768);
        const float4 a0 = *reinterpret_cast<const float4*>(&As[idx]);
        const float4 a1 = *reinterpret_cast<const float4*>(&As[idx + 256]);
        const float4 a2 = *reinterpret_cast<const float4*>(&As[idx + 512]);
        const float4 a3 = *reinterpret_cast<const float4*>(&As[idx + 768]);
        s0 = fmaf(a0.x, d0.x, s0); s0 = fmaf(a0.y, d0.y, s0);
        s0 = fmaf(a0.z, d0.z, s0); s0 = fmaf(a0.w, d0.w, s0);
        s1 = fmaf(a1.x, d1.x, s1); s1 = fmaf(a1.y, d1.y, s1);
        s1 = fmaf(a1.z, d1.z, s1); s1 = fmaf(a1.w, d1.w, s1);
        s2 = fmaf(a2.x, d2.x, s2); s2 = fmaf(a2.y, d2.y, s2);
        s2 = fmaf(a2.z, d2.z, s2); s2 = fmaf(a2.w, d2.w, s2);
        s3 = fmaf(a3.x, d3.x, s3); s3 = fmaf(a3.y, d3.y, s3);
        s3 = fmaf(a3.z, d3.z, s3); s3 = fmaf(a3.w, d3.w, s3);
    }

    float s = (s0 + s1) + (s2 + s3);

    #pragma unroll
    for (int off = 32; off > 0; off >>= 1)
        s += __shfl_down(s, off, 64);

    if (lane == 0) out[base_plane + wv] = s;
}

extern "C" void kernel_launch(void* const* d_in, const int* in_sizes, int n_in,
                              void* d_out, int out_size, void* d_ws, size_t ws_size,
                              hipStream_t stream) {
    const float* data   = (const float*)d_in[0];  // fp32 [32,256,64,64]
    const float* offset = (const float*)d_in[1];  // fp32 [32,2,64,64]
    const float* ts     = (const float*)d_in[2];  // fp32 scalar

    float* A   = (float*)d_ws;   // [32, 4096] fp32 = 512 KiB scratch
    float* out = (float*)d_out;  // [32, 256] fp32

    weight_map_kernel<<<BATCH, 256, 0, stream>>>(offset, ts, A);
    dot_kernel<<<(BATCH * CHAN) / 4, 256, 0, stream>>>(data, A, out);
}